// Round 2
// baseline (1027.004 us; speedup 1.0000x reference)
//
#include <hip/hip_runtime.h>
#include <hip/hip_bf16.h>

// QuantLinear: y[t,o] = (sum_k x[t,k] * (q[o,k]-8)) * scale[o] + bias[o]
// Scale factors out of the K-reduction -> bf16 MFMA GEMM on (q-8) (exact in
// bf16), scale/bias in epilogue. Round 2:
//  - GEMM: BK=64 + XOR chunk swizzle (kc' = kc ^ (row&7)) -> conflict-free
//    ds_read_b128 (round 1: +4 cyc/b128 from 4x quarter-wave conflicts) and
//    half the barrier count.
//  - converts: 4x16B ILP per thread, grid-strided.

#define AS1 __attribute__((address_space(1)))
#define AS3 __attribute__((address_space(3)))

typedef __attribute__((ext_vector_type(8))) short short8;
typedef __attribute__((ext_vector_type(4))) float f32x4;

static constexpr int IN_F   = 4096;     // K
static constexpr int OUT_F  = 14336;    // N
static constexpr int TOKENS = 2 * 2048; // M

// ---------------- conversion kernels ----------------

__device__ __forceinline__ unsigned short bf16_rne(float f) {
    unsigned int u = __float_as_uint(f);
    u += 0x7fffu + ((u >> 16) & 1u);
    return (unsigned short)(u >> 16);
}

__device__ __forceinline__ ushort4 cvt_w4(int4 v) {
    ushort4 r;  // small ints exact in bf16: truncate fp32 bits
    r.x = (unsigned short)(__float_as_uint((float)(v.x - 8)) >> 16);
    r.y = (unsigned short)(__float_as_uint((float)(v.y - 8)) >> 16);
    r.z = (unsigned short)(__float_as_uint((float)(v.z - 8)) >> 16);
    r.w = (unsigned short)(__float_as_uint((float)(v.w - 8)) >> 16);
    return r;
}

__device__ __forceinline__ ushort4 cvt_x4(float4 v) {
    ushort4 r;
    r.x = bf16_rne(v.x); r.y = bf16_rne(v.y);
    r.z = bf16_rne(v.z); r.w = bf16_rne(v.w);
    return r;
}

// 58,720,256 w elems = 14,680,064 int4-chunks = 4 per thread * 14336 blocks * 256
__global__ void convert_w_kernel(const int4* __restrict__ q,
                                 ushort4* __restrict__ wb) {
    const size_t G = (size_t)14336 * 256;
    size_t i = (size_t)blockIdx.x * blockDim.x + threadIdx.x;
    int4 v0 = q[i];
    int4 v1 = q[i + G];
    int4 v2 = q[i + 2 * G];
    int4 v3 = q[i + 3 * G];
    wb[i]         = cvt_w4(v0);
    wb[i + G]     = cvt_w4(v1);
    wb[i + 2 * G] = cvt_w4(v2);
    wb[i + 3 * G] = cvt_w4(v3);
}

// 16,777,216 x elems = 4,194,304 float4-chunks = 4 per thread * 4096 blocks * 256
__global__ void convert_x_kernel(const float4* __restrict__ x,
                                 ushort4* __restrict__ xb) {
    const size_t G = (size_t)4096 * 256;
    size_t i = (size_t)blockIdx.x * blockDim.x + threadIdx.x;
    float4 v0 = x[i];
    float4 v1 = x[i + G];
    float4 v2 = x[i + 2 * G];
    float4 v3 = x[i + 3 * G];
    xb[i]         = cvt_x4(v0);
    xb[i + G]     = cvt_x4(v1);
    xb[i + 2 * G] = cvt_x4(v2);
    xb[i + 3 * G] = cvt_x4(v3);
}

// ---------------- GEMM: C[M,N] = A[M,K] * B[N,K]^T, scale/bias epilogue -----
// 128x128 tile, BK=64, 4 waves x (4x4 of 16x16x32 bf16 MFMA) x 2 k-halves.
// LDS: chunk swizzle kc' = kc ^ (row&7); slot s holds (row=s>>3, kc=(s&7)^(row&7)).

__global__ __launch_bounds__(256)
void gemm_bt_kernel(const unsigned short* __restrict__ A,   // bf16 [M,K]
                    const unsigned short* __restrict__ B,   // bf16 [N,K]
                    const float* __restrict__ scale,        // [N]
                    const float* __restrict__ bias,         // [N]
                    float* __restrict__ C) {                // [M,N]
    constexpr int K  = IN_F;
    constexpr int N  = OUT_F;
    constexpr int BK = 64;

    __shared__ __align__(16) unsigned short sA[128 * BK]; // 16 KiB
    __shared__ __align__(16) unsigned short sB[128 * BK]; // 16 KiB

    const int tid  = threadIdx.x;
    const int wave = tid >> 6;
    const int lane = tid & 63;
    const int l16  = lane & 15;
    const int lq   = lane >> 4;            // 0..3

    const int mBase = blockIdx.y * 128;
    const int nBase = blockIdx.x * 128;
    const int wm = (wave >> 1) * 64;
    const int wn = (wave & 1) * 64;

    // staging: slot s = c*256 + tid  ->  row = s>>3, swizzled chunk = (s&7)^(row&7)
    int srow[4], soff[4];
#pragma unroll
    for (int c = 0; c < 4; ++c) {
        const int s = c * 256 + tid;
        srow[c] = s >> 3;
        soff[c] = (((s & 7) ^ (srow[c] & 7)) * 8);   // shorts within row
    }

    const unsigned short* gA = A + (size_t)mBase * K;
    const unsigned short* gB = B + (size_t)nBase * K;

    f32x4 acc[4][4] = {};

    for (int k0 = 0; k0 < K; k0 += BK) {
#pragma unroll
        for (int c = 0; c < 4; ++c) {
            const int s = c * 256 + tid;
            __builtin_amdgcn_global_load_lds(
                (const AS1 void*)(gA + (size_t)srow[c] * K + k0 + soff[c]),
                (AS3 void*)(sA + s * 8), 16, 0, 0);
            __builtin_amdgcn_global_load_lds(
                (const AS1 void*)(gB + (size_t)srow[c] * K + k0 + soff[c]),
                (AS3 void*)(sB + s * 8), 16, 0, 0);
        }
        __syncthreads();

#pragma unroll
        for (int h = 0; h < 2; ++h) {
            // fragment k-chunk (unswizzled) = h*4 + lq; row&7 == l16&7
            const int xk = ((h * 4 + lq) ^ (l16 & 7)) * 8;
            short8 af[4], bfr[4];
#pragma unroll
            for (int i = 0; i < 4; ++i)
                af[i] = *(const short8*)&sA[(wm + i * 16 + l16) * BK + xk];
#pragma unroll
            for (int j = 0; j < 4; ++j)
                bfr[j] = *(const short8*)&sB[(wn + j * 16 + l16) * BK + xk];

#pragma unroll
            for (int i = 0; i < 4; ++i)
#pragma unroll
                for (int j = 0; j < 4; ++j)
                    acc[i][j] = __builtin_amdgcn_mfma_f32_16x16x32_bf16(
                        af[i], bfr[j], acc[i][j], 0, 0, 0);
        }
        __syncthreads();
    }

    // epilogue: C/D layout col = lane&15, row = (lane>>4)*4 + reg
#pragma unroll
    for (int j = 0; j < 4; ++j) {
        const int n = nBase + wn + j * 16 + l16;
        const float s  = scale[n];
        const float bb = bias[n];
#pragma unroll
        for (int i = 0; i < 4; ++i) {
            const int m0 = mBase + wm + i * 16 + lq * 4;
#pragma unroll
            for (int r = 0; r < 4; ++r)
                C[(size_t)(m0 + r) * N + n] = acc[i][j][r] * s + bb;
        }
    }
}

// ---------------- launch ----------------

extern "C" void kernel_launch(void* const* d_in, const int* in_sizes, int n_in,
                              void* d_out, int out_size, void* d_ws, size_t ws_size,
                              hipStream_t stream) {
    const float* x      = (const float*)d_in[0];  // [2,2048,4096] fp32
    const int*   wq     = (const int*)d_in[1];    // [14336,4096] int32 in [0,16)
    const float* wscale = (const float*)d_in[2];  // [14336,1]
    const float* wbias  = (const float*)d_in[3];  // [14336]
    float* out = (float*)d_out;                   // [2,2048,14336] fp32

    unsigned short* wbf = (unsigned short*)d_ws;          // 117.4 MB
    unsigned short* xbf = wbf + (size_t)OUT_F * IN_F;     // +33.6 MB

    convert_w_kernel<<<14336, 256, 0, stream>>>((const int4*)wq, (ushort4*)wbf);
    convert_x_kernel<<<4096, 256, 0, stream>>>((const float4*)x, (ushort4*)xbf);

    dim3 grid(OUT_F / 128, TOKENS / 128);  // (112, 32)
    gemm_bt_kernel<<<grid, 256, 0, stream>>>(xbf, wbf, wscale, wbias, out);
}

// Round 3
// 991.737 us; speedup vs baseline: 1.0356x; 1.0356x over previous
//
#include <hip/hip_runtime.h>
#include <hip/hip_bf16.h>

// QuantLinear: y[t,o] = (sum_k x[t,k] * (q[o,k]-8)) * scale[o] + bias[o]
// Scale factors out of the K-reduction -> bf16 MFMA GEMM on (q-8) (exact in
// bf16), scale/bias in epilogue.
// Round 3: round-1 structure (BK=32, 16 KiB LDS, simple width-16 staging)
//   + inner shape 32x32x16 (MFMA pipe: ~4096 vs ~3378 FLOP/cyc, half the
//     issue count) + 2-bit XOR chunk swizzle (conflict-free frag reads,
//     identical global coalescing).
// Round-2 lesson: LDS bank conflicts were NOT binding; BK=64 cost occupancy.

#define AS1 __attribute__((address_space(1)))
#define AS3 __attribute__((address_space(3)))

typedef __attribute__((ext_vector_type(8))) short short8;
typedef __attribute__((ext_vector_type(16))) float f32x16;

static constexpr int IN_F   = 4096;     // K
static constexpr int OUT_F  = 14336;    // N
static constexpr int TOKENS = 2 * 2048; // M

// ---------------- conversion kernels ----------------

__device__ __forceinline__ unsigned short bf16_rne(float f) {
    unsigned int u = __float_as_uint(f);
    u += 0x7fffu + ((u >> 16) & 1u);
    return (unsigned short)(u >> 16);
}

__global__ void convert_x_kernel(const float4* __restrict__ x,
                                 ushort4* __restrict__ xb) {
    size_t i = (size_t)blockIdx.x * blockDim.x + threadIdx.x;
    float4 v = x[i];
    ushort4 r;
    r.x = bf16_rne(v.x); r.y = bf16_rne(v.y);
    r.z = bf16_rne(v.z); r.w = bf16_rne(v.w);
    xb[i] = r;
}

__global__ void convert_w_kernel(const int4* __restrict__ q,
                                 ushort4* __restrict__ wb) {
    size_t i = (size_t)blockIdx.x * blockDim.x + threadIdx.x;
    int4 v = q[i];
    ushort4 r;  // ints in [-8,7] are exact in bf16: truncate fp32 bits
    r.x = (unsigned short)(__float_as_uint((float)(v.x - 8)) >> 16);
    r.y = (unsigned short)(__float_as_uint((float)(v.y - 8)) >> 16);
    r.z = (unsigned short)(__float_as_uint((float)(v.z - 8)) >> 16);
    r.w = (unsigned short)(__float_as_uint((float)(v.w - 8)) >> 16);
    wb[i] = r;
}

// ---------------- GEMM: C[M,N] = A[M,K] * B[N,K]^T, scale/bias epilogue -----
// 128x128 tile, BK=32, 4 waves; each wave: 64x64 as 2x2 of mfma_f32_32x32x16.
// LDS rows of 64 B = 4 chunks of 16 B; physical chunk p holds logical chunk
// q = p ^ (row&3) (XOR applied on the global-read side; global_load_lds dest
// stays the contiguous tid*16 required by the wave-uniform-base rule).

__global__ __launch_bounds__(256)
void gemm_bt_kernel(const unsigned short* __restrict__ A,   // bf16 [M,K]
                    const unsigned short* __restrict__ B,   // bf16 [N,K]
                    const float* __restrict__ scale,        // [N]
                    const float* __restrict__ bias,         // [N]
                    float* __restrict__ C) {                // [M,N]
    constexpr int K  = IN_F;
    constexpr int N  = OUT_F;
    constexpr int BK = 32;

    __shared__ __align__(16) unsigned short sA[128 * BK]; // 8 KiB
    __shared__ __align__(16) unsigned short sB[128 * BK]; // 8 KiB

    const int tid  = threadIdx.x;
    const int wave = tid >> 6;
    const int lane = tid & 63;
    const int l31  = lane & 31;
    const int g    = lane >> 5;            // half-wave 0/1

    const int mBase = blockIdx.y * 128;
    const int nBase = blockIdx.x * 128;
    const int wm = (wave >> 1) * 64;
    const int wn = (wave & 1) * 64;

    // staging: thread t -> row t>>2, logical chunk (t&3)^(row&3), LDS slot t*16B
    const int sr = tid >> 2;
    const int sc = ((tid & 3) ^ (sr & 3)) * 8;   // shorts

    const unsigned short* gA = A + (size_t)(mBase + sr) * K + sc;
    const unsigned short* gB = B + (size_t)(nBase + sr) * K + sc;
    unsigned short* lA = &sA[tid * 8];
    unsigned short* lB = &sB[tid * 8];

    f32x16 acc[2][2] = {};

    for (int k0 = 0; k0 < K; k0 += BK) {
        __builtin_amdgcn_global_load_lds((const AS1 void*)(gA + k0),
                                         (AS3 void*)lA, 16, 0, 0);
        __builtin_amdgcn_global_load_lds((const AS1 void*)(gA + (size_t)64 * K + k0),
                                         (AS3 void*)(lA + 64 * BK), 16, 0, 0);
        __builtin_amdgcn_global_load_lds((const AS1 void*)(gB + k0),
                                         (AS3 void*)lB, 16, 0, 0);
        __builtin_amdgcn_global_load_lds((const AS1 void*)(gB + (size_t)64 * K + k0),
                                         (AS3 void*)(lB + 64 * BK), 16, 0, 0);
        __syncthreads();

#pragma unroll
        for (int h = 0; h < 2; ++h) {          // two K=16 steps
            const int q = h * 2 + g;           // logical 16B chunk for this frag
            short8 af[2], bfr[2];
#pragma unroll
            for (int i = 0; i < 2; ++i) {
                const int r = wm + i * 32 + l31;
                af[i] = *(const short8*)&sA[r * BK + (q ^ (r & 3)) * 8];
            }
#pragma unroll
            for (int j = 0; j < 2; ++j) {
                const int r = wn + j * 32 + l31;
                bfr[j] = *(const short8*)&sB[r * BK + (q ^ (r & 3)) * 8];
            }
#pragma unroll
            for (int i = 0; i < 2; ++i)
#pragma unroll
                for (int j = 0; j < 2; ++j)
                    acc[i][j] = __builtin_amdgcn_mfma_f32_32x32x16_bf16(
                        af[i], bfr[j], acc[i][j], 0, 0, 0);
        }
        __syncthreads();
    }

    // epilogue: C/D layout col = lane&31, row = (reg&3) + 8*(reg>>2) + 4*(lane>>5)
#pragma unroll
    for (int j = 0; j < 2; ++j) {
        const int n = nBase + wn + j * 32 + l31;
        const float s  = scale[n];
        const float bb = bias[n];
#pragma unroll
        for (int i = 0; i < 2; ++i) {
            const int m0 = mBase + wm + i * 32 + 4 * g;
#pragma unroll
            for (int reg = 0; reg < 16; ++reg) {
                const int row = (reg & 3) + 8 * (reg >> 2);
                C[(size_t)(m0 + row) * N + n] = acc[i][j][reg] * s + bb;
            }
        }
    }
}

// ---------------- launch ----------------

extern "C" void kernel_launch(void* const* d_in, const int* in_sizes, int n_in,
                              void* d_out, int out_size, void* d_ws, size_t ws_size,
                              hipStream_t stream) {
    const float* x      = (const float*)d_in[0];  // [2,2048,4096] fp32
    const int*   wq     = (const int*)d_in[1];    // [14336,4096] int32 in [0,16)
    const float* wscale = (const float*)d_in[2];  // [14336,1]
    const float* wbias  = (const float*)d_in[3];  // [14336]
    float* out = (float*)d_out;                   // [2,2048,14336] fp32

    unsigned short* wbf = (unsigned short*)d_ws;          // 117.4 MB
    unsigned short* xbf = wbf + (size_t)OUT_F * IN_F;     // +33.6 MB

    convert_w_kernel<<<57344, 256, 0, stream>>>((const int4*)wq, (ushort4*)wbf);
    convert_x_kernel<<<16384, 256, 0, stream>>>((const float4*)x, (ushort4*)xbf);

    dim3 grid(OUT_F / 128, TOKENS / 128);  // (112, 32)
    gemm_bt_kernel<<<grid, 256, 0, stream>>>(xbf, wbf, wscale, wbias, out);
}